// Round 4
// baseline (214.607 us; speedup 1.0000x reference)
//
#include <hip/hip_runtime.h>

#define N_NODES 50000
#define N_EDGES 800000
#define SCAN_BLOCKS 196              // ceil(50000/256)
#define SENTINEL 50000               // zero-row index in gather tables
#define PAD_CAP (N_EDGES + 7 * N_NODES)  // max padded slots
#define EQ (N_EDGES / 4)             // edges per thread-pass in hist/place

// ---------------- degree histogram: 4 independent chains/thread ----------------
__global__ void hist_kernel(const int* __restrict__ edge_dst,
                            int* __restrict__ deg) {
    int t = blockIdx.x * blockDim.x + threadIdx.x;
    if (t >= EQ) return;
#pragma unroll
    for (int k = 0; k < 4; ++k) atomicAdd(&deg[edge_dst[t + k * EQ]], 1);
}

// ---------------- scan step 1: per-block exclusive scan of PADDED deg ----------------
__global__ void scan1_kernel(const int* __restrict__ deg,
                             int* __restrict__ prs,
                             int* __restrict__ partials) {
    __shared__ int sm[256];
    int tid = threadIdx.x;
    int i = blockIdx.x * 256 + tid;
    int v = (i < N_NODES) ? ((deg[i] + 7) & ~7) : 0;   // pad to multiple of 8
    sm[tid] = v;
    __syncthreads();
    int x = v;
    for (int off = 1; off < 256; off <<= 1) {
        int y = (tid >= off) ? sm[tid - off] : 0;
        __syncthreads();
        x += y;
        sm[tid] = x;
        __syncthreads();
    }
    if (i < N_NODES) prs[i] = x - v;       // exclusive
    if (tid == 255) partials[blockIdx.x] = x;
}

// ---------------- scan step 2: scan block totals (1 block) ----------------
__global__ void scan2_kernel(int* __restrict__ partials) {
    __shared__ int sm[256];
    int tid = threadIdx.x;
    int v = (tid < SCAN_BLOCKS) ? partials[tid] : 0;
    sm[tid] = v;
    __syncthreads();
    int x = v;
    for (int off = 1; off < 256; off <<= 1) {
        int y = (tid >= off) ? sm[tid - off] : 0;
        __syncthreads();
        x += y;
        sm[tid] = x;
        __syncthreads();
    }
    if (tid < SCAN_BLOCKS) partials[tid] = x - v;
}

// ---------------- scan step 3: finalize prs, cursor, inv_deg ----------------
__global__ void scan3_kernel(int* __restrict__ prs,
                             const int* __restrict__ partials,
                             const int* __restrict__ deg,
                             int* __restrict__ cursor,
                             float* __restrict__ inv_deg) {
    int i = blockIdx.x * blockDim.x + threadIdx.x;
    if (i < N_NODES) {
        int rs = prs[i] + partials[i >> 8];
        prs[i] = rs;
        cursor[i] = rs;
        int d = deg[i];
        inv_deg[i] = 1.0f / (float)max(d, 1);
        if (i == N_NODES - 1) prs[N_NODES] = rs + ((d + 7) & ~7);
    }
}

// ---------------- place: counting-sort by dst, 4 chains/thread ----------------
__global__ void place_kernel(const int* __restrict__ edge_src,
                             const int* __restrict__ edge_dst,
                             int* __restrict__ cursor,
                             unsigned short* __restrict__ sorted_src) {
    int t = blockIdx.x * blockDim.x + threadIdx.x;
    if (t >= EQ) return;
#pragma unroll
    for (int k = 0; k < 4; ++k) {
        int e = t + k * EQ;
        int d = edge_dst[e];
        int pos = atomicAdd(&cursor[d], 1);
        sorted_src[pos] = (unsigned short)edge_src[e];
    }
}

// ---------------- bf16x2 pack (RNE) ----------------
__device__ __forceinline__ unsigned int pack_bf16x2(float x, float y) {
    unsigned int bx = __float_as_uint(x);
    unsigned int by = __float_as_uint(y);
    bx = (bx + 0x7fffu + ((bx >> 16) & 1u)) >> 16;
    by = (by + 0x7fffu + ((by >> 16) & 1u)) & 0xffff0000u;
    return (bx & 0xffffu) | by;
}

// ---------------- convert h -> bf16x2; zero sentinel rows of all tables ----------------
__global__ void convert_kernel(const float* __restrict__ h,
                               unsigned int* __restrict__ hb,
                               unsigned int* __restrict__ u1b,
                               unsigned int* __restrict__ u2b) {
    int idx = blockIdx.x * blockDim.x + threadIdx.x;  // over (N+1)*64
    if (idx >= (N_NODES + 1) * 64) return;
    if ((idx >> 6) == N_NODES) {
        hb[idx] = 0u;
        u1b[idx] = 0u;
        u2b[idx] = 0u;
    } else {
        float2 v = reinterpret_cast<const float2*>(h)[idx];
        hb[idx] = pack_bf16x2(v.x, v.y);
    }
}

// ---------------- pure gather layer: u_out = M * src (bf16 -> bf16) ----------------
// One wave per node. 4 groups x 16 lanes; group g handles edges j+g, j+4+g.
// Pad slots masked by POSITION (index -> SENTINEL zero row); no fill pass needed.
__global__ void sage_layer_kernel(const unsigned short* __restrict__ sorted_src,
                                  const int* __restrict__ prs,
                                  const int* __restrict__ deg,
                                  const float* __restrict__ inv_deg,
                                  const unsigned int* __restrict__ src,
                                  unsigned int* __restrict__ u_out) {
    int gid = blockIdx.x * blockDim.x + threadIdx.x;
    int node = gid >> 6;
    int lane = gid & 63;
    if (node >= N_NODES) return;
    int g = lane >> 4;
    int sub = lane & 15;

    int start = prs[node];
    int end = prs[node + 1];          // padded: (end-start) % 8 == 0
    int dend = start + deg[node];     // real end

    float a0 = 0.f, a1 = 0.f, a2 = 0.f, a3 = 0.f;
    float a4 = 0.f, a5 = 0.f, a6 = 0.f, a7 = 0.f;

    const uint4* s4 = reinterpret_cast<const uint4*>(src);
    for (int j = start; j < end; j += 8) {
        int sl0 = j + g;
        int sl1 = j + 4 + g;
        int i0 = sorted_src[sl0];     // in-bounds always; value may be garbage in pad
        int i1 = sorted_src[sl1];
        if (sl0 >= dend) i0 = SENTINEL;   // mask by position
        if (sl1 >= dend) i1 = SENTINEL;
        uint4 v0 = s4[i0 * 16 + sub];
        uint4 v1 = s4[i1 * 16 + sub];
        a0 += __uint_as_float(v0.x << 16);
        a1 += __uint_as_float(v0.x & 0xffff0000u);
        a2 += __uint_as_float(v0.y << 16);
        a3 += __uint_as_float(v0.y & 0xffff0000u);
        a4 += __uint_as_float(v0.z << 16);
        a5 += __uint_as_float(v0.z & 0xffff0000u);
        a6 += __uint_as_float(v0.w << 16);
        a7 += __uint_as_float(v0.w & 0xffff0000u);
        a0 += __uint_as_float(v1.x << 16);
        a1 += __uint_as_float(v1.x & 0xffff0000u);
        a2 += __uint_as_float(v1.y << 16);
        a3 += __uint_as_float(v1.y & 0xffff0000u);
        a4 += __uint_as_float(v1.z << 16);
        a5 += __uint_as_float(v1.z & 0xffff0000u);
        a6 += __uint_as_float(v1.w << 16);
        a7 += __uint_as_float(v1.w & 0xffff0000u);
    }

    a0 += __shfl_xor(a0, 16); a0 += __shfl_xor(a0, 32);
    a1 += __shfl_xor(a1, 16); a1 += __shfl_xor(a1, 32);
    a2 += __shfl_xor(a2, 16); a2 += __shfl_xor(a2, 32);
    a3 += __shfl_xor(a3, 16); a3 += __shfl_xor(a3, 32);
    a4 += __shfl_xor(a4, 16); a4 += __shfl_xor(a4, 32);
    a5 += __shfl_xor(a5, 16); a5 += __shfl_xor(a5, 32);
    a6 += __shfl_xor(a6, 16); a6 += __shfl_xor(a6, 32);
    a7 += __shfl_xor(a7, 16); a7 += __shfl_xor(a7, 32);

    if (g == 0) {
        float inv = inv_deg[node];
        uint4 w;
        w.x = pack_bf16x2(a0 * inv, a1 * inv);
        w.y = pack_bf16x2(a2 * inv, a3 * inv);
        w.z = pack_bf16x2(a4 * inv, a5 * inv);
        w.w = pack_bf16x2(a6 * inv, a7 * inv);
        reinterpret_cast<uint4*>(u_out)[node * 16 + sub] = w;  // 256 B/row coalesced
    }
}

// ---------------- final combine: res = (17/6)h + 3u1 + 1.5u2 + (1/3)u3 ----------------
__device__ __forceinline__ float blo(unsigned int w) { return __uint_as_float(w << 16); }
__device__ __forceinline__ float bhi(unsigned int w) { return __uint_as_float(w & 0xffff0000u); }

__global__ void combine_kernel(const float* __restrict__ h,
                               const unsigned int* __restrict__ u1b,
                               const unsigned int* __restrict__ u2b,
                               const unsigned int* __restrict__ u3b,
                               float* __restrict__ res) {
    int i = blockIdx.x * blockDim.x + threadIdx.x;  // over N*32 float4s
    if (i >= N_NODES * 32) return;
    float4 hv = reinterpret_cast<const float4*>(h)[i];
    uint2 w1 = reinterpret_cast<const uint2*>(u1b)[i];
    uint2 w2 = reinterpret_cast<const uint2*>(u2b)[i];
    uint2 w3 = reinterpret_cast<const uint2*>(u3b)[i];
    const float C0 = 2.8333333f, C1 = 3.0f, C2 = 1.5f, C3 = 0.33333334f;
    float4 r;
    r.x = C0 * hv.x + C1 * blo(w1.x) + C2 * blo(w2.x) + C3 * blo(w3.x);
    r.y = C0 * hv.y + C1 * bhi(w1.x) + C2 * bhi(w2.x) + C3 * bhi(w3.x);
    r.z = C0 * hv.z + C1 * blo(w1.y) + C2 * blo(w2.y) + C3 * blo(w3.y);
    r.w = C0 * hv.w + C1 * bhi(w1.y) + C2 * bhi(w2.y) + C3 * bhi(w3.y);
    reinterpret_cast<float4*>(res)[i] = r;
}

extern "C" void kernel_launch(void* const* d_in, const int* in_sizes, int n_in,
                              void* d_out, int out_size, void* d_ws, size_t ws_size,
                              hipStream_t stream) {
    const float* h        = (const float*)d_in[0];
    const int*   edge_src = (const int*)d_in[1];
    const int*   edge_dst = (const int*)d_in[2];
    float*       res      = (float*)d_out;

    // Workspace layout (~44.3 MB; 52 MB proven available in round 1):
    char* ws = (char*)d_ws;
    int* deg               = (int*)(ws + 0x000000);   // N ints
    int* cursor            = (int*)(ws + 0x040000);   // N ints
    int* prs               = (int*)(ws + 0x080000);   // N+1 ints
    int* partials          = (int*)(ws + 0x0C0000);   // 256 ints
    float* inv_deg         = (float*)(ws + 0x100000); // N floats
    unsigned short* sorted = (unsigned short*)(ws + 0x140000);  // PAD_CAP u16 (2.3 MB)
    unsigned int* hb       = (unsigned int*)(ws + 0x0400000);   // (N+1)*64 u32 (12.8 MB)
    unsigned int* u1b      = (unsigned int*)(ws + 0x1100000);   // (N+1)*64 u32
    unsigned int* u2b      = (unsigned int*)(ws + 0x1E00000);   // (N+1)*64 u32
    unsigned int* u3b      = hb;  // hb dead after layer 1; reuse for u3

    const int BLK = 256;

    // ---- CSR build (padded, dst-sorted; pad slots left uninitialized) ----
    hipMemsetAsync(deg, 0, N_NODES * sizeof(int), stream);
    hist_kernel<<<(EQ + BLK - 1) / BLK, BLK, 0, stream>>>(edge_dst, deg);
    scan1_kernel<<<SCAN_BLOCKS, BLK, 0, stream>>>(deg, prs, partials);
    scan2_kernel<<<1, BLK, 0, stream>>>(partials);
    scan3_kernel<<<SCAN_BLOCKS, BLK, 0, stream>>>(prs, partials, deg, cursor, inv_deg);
    place_kernel<<<(EQ + BLK - 1) / BLK, BLK, 0, stream>>>(
        edge_src, edge_dst, cursor, sorted);

    // ---- h -> bf16 (+ zero sentinel rows of hb, u1b, u2b) ----
    convert_kernel<<<((N_NODES + 1) * 64 + BLK - 1) / BLK, BLK, 0, stream>>>(
        h, hb, u1b, u2b);

    // ---- pure gather layers: u1 = M hb, u2 = M u1, u3 = M u2 ----
    const int LGRID = (N_NODES * 64) / BLK;  // 12500 blocks
    sage_layer_kernel<<<LGRID, BLK, 0, stream>>>(sorted, prs, deg, inv_deg, hb, u1b);
    sage_layer_kernel<<<LGRID, BLK, 0, stream>>>(sorted, prs, deg, inv_deg, u1b, u2b);
    sage_layer_kernel<<<LGRID, BLK, 0, stream>>>(sorted, prs, deg, inv_deg, u2b, u3b);

    // ---- res = (17/6)h + 3u1 + 1.5u2 + (1/3)u3 ----
    combine_kernel<<<(N_NODES * 32 + BLK - 1) / BLK, BLK, 0, stream>>>(
        h, u1b, u2b, u3b, res);
}